// Round 6
// baseline (69.637 us; speedup 1.0000x reference)
//
#include <hip/hip_runtime.h>
#include <hip/hip_bf16.h>

#define NN 2048
#define FIN 512
#define FOUT 128
#define NEGV -9e15f
#define ALPHAV 0.2f
#define LOG2E 1.44269504088896340736f

typedef __attribute__((ext_vector_type(8))) short bf16x8;
typedef __attribute__((ext_vector_type(4))) float f32x4;

__device__ __forceinline__ unsigned cvt_pk_bf16(float lo, float hi) {
    unsigned r;
    asm("v_cvt_pk_bf16_f32 %0, %1, %2" : "=v"(r) : "v"(lo), "v"(hi));
    return r;   // low16 = bf16(lo), high16 = bf16(hi), RNE
}

__device__ __forceinline__ unsigned short f32_to_bf16(float f) {
    unsigned int u = __float_as_uint(f);
    unsigned int r = (u + 0x7FFFu + ((u >> 16) & 1u)) >> 16;   // RNE
    return (unsigned short)r;
}

// ---------------- Kernel W: repack W -> bf16 hi/lo MFMA-B fragments ----------------
__global__ void k_wrep(const float* __restrict__ W,
                       unsigned short* __restrict__ whi,
                       unsigned short* __restrict__ wlo) {
    int kt = blockIdx.x >> 3;
    int t_o = blockIdx.x & 7;
    int l = threadIdx.x;
    int lr = l & 15, lg = l >> 4;
    unsigned short vh[8], vl[8];
#pragma unroll
    for (int jj = 0; jj < 8; jj++) {
        float f = W[(size_t)(kt * 32 + lg * 8 + jj) * FOUT + t_o * 16 + lr];
        unsigned short h = f32_to_bf16(f);
        float hf = __uint_as_float(((unsigned)h) << 16);
        vh[jj] = h;
        vl[jj] = f32_to_bf16(f - hf);
    }
    size_t o = ((size_t)(kt * 8 + t_o) * 64 + l) * 8;
    *(uint4*)(whi + o) = *(const uint4*)vh;
    *(uint4*)(wlo + o) = *(const uint4*)vl;
}

// ---------------- Kernel P: fused {adj->bitmask stream} + {h=x@W MFMA, t1/t2, repack} ----------------
// grid = 2048 (mask) + 512 (h) = 2560 blocks, 256 threads.
// Mask path: block handles 4 rows (one per wave); wave ballots 64 j's/iter.
//   maskw[(b*64 + j/32)*2048 + i] bit (j%32) = (adj[b][i][j]==d1 || ==d2)
// H path: identical to previous k_h (16 rows x 128 cols, split-bf16 MFMA);
//   t1/t2 stored pre-scaled by log2(e).
__global__ void __launch_bounds__(256) k_prep(const float* __restrict__ x,
                                              const unsigned short* __restrict__ whi,
                                              const unsigned short* __restrict__ wlo,
                                              const float* __restrict__ a1,
                                              const float* __restrict__ a2,
                                              const int* __restrict__ adj,
                                              const int* __restrict__ d1p,
                                              const int* __restrict__ d2p,
                                              unsigned short* __restrict__ hb,
                                              float* __restrict__ t1,
                                              float* __restrict__ t2,
                                              unsigned* __restrict__ maskw) {
    __shared__ float lds_t1[4][16];
    __shared__ float lds_t2[4][16];
    int tid = threadIdx.x;
    int wv = tid >> 6, l = tid & 63;
    int lr = l & 15, lg = l >> 4;

    if (blockIdx.x < 2048) {
        // ---------- mask compression path ----------
        int d1 = d1p[0], d2 = d2p[0];
        int row = blockIdx.x * 4 + wv;            // b*2048 + i
        int b = row >> 11, i = row & 2047;
        const int* ap = adj + (size_t)row * NN + l;
        unsigned* mbase = maskw + (size_t)b * 64 * NN + i;
#pragma unroll 8
        for (int k = 0; k < 32; k++) {
            int a = ap[k * 64];
            unsigned long long bal = __ballot(a == d1 || a == d2);
            if (l == 0) {
                mbase[(size_t)(2 * k) * NN]     = (unsigned)bal;
                mbase[(size_t)(2 * k + 1) * NN] = (unsigned)(bal >> 32);
            }
        }
        return;
    }

    // ---------- h path ----------
    int blk = blockIdx.x - 2048;
    int row0 = blk * 16;

    const float* xp = x + (size_t)(row0 + lr) * FIN + lg * 8;
    const unsigned short* wb = whi + (size_t)(2 * wv) * 512 + l * 8;
    const unsigned short* lb = wlo + (size_t)(2 * wv) * 512 + l * 8;

    f32x4 acc0 = {0.f, 0.f, 0.f, 0.f};
    f32x4 acc1 = {0.f, 0.f, 0.f, 0.f};

#pragma unroll 2
    for (int kt = 0; kt < FIN / 32; kt++) {
        float4 xa = *(const float4*)(xp + kt * 32);
        float4 xb = *(const float4*)(xp + kt * 32 + 4);
        bf16x8 wh0 = *(const bf16x8*)(wb + (size_t)kt * 4096);
        bf16x8 wh1 = *(const bf16x8*)(wb + (size_t)kt * 4096 + 512);
        bf16x8 wl0 = *(const bf16x8*)(lb + (size_t)kt * 4096);
        bf16x8 wl1 = *(const bf16x8*)(lb + (size_t)kt * 4096 + 512);

        float f[8] = {xa.x, xa.y, xa.z, xa.w, xb.x, xb.y, xb.z, xb.w};
        unsigned uh[4], ul[4];
#pragma unroll
        for (int w = 0; w < 4; w++) {
            uh[w] = cvt_pk_bf16(f[2 * w], f[2 * w + 1]);
            float r0 = f[2 * w]     - __uint_as_float(uh[w] << 16);
            float r1 = f[2 * w + 1] - __uint_as_float(uh[w] & 0xffff0000u);
            ul[w] = cvt_pk_bf16(r0, r1);
        }
        bf16x8 xh = *(const bf16x8*)uh;
        bf16x8 xl = *(const bf16x8*)ul;

        acc0 = __builtin_amdgcn_mfma_f32_16x16x32_bf16(xh, wh0, acc0, 0, 0, 0);
        acc0 = __builtin_amdgcn_mfma_f32_16x16x32_bf16(xl, wh0, acc0, 0, 0, 0);
        acc0 = __builtin_amdgcn_mfma_f32_16x16x32_bf16(xh, wl0, acc0, 0, 0, 0);
        acc1 = __builtin_amdgcn_mfma_f32_16x16x32_bf16(xh, wh1, acc1, 0, 0, 0);
        acc1 = __builtin_amdgcn_mfma_f32_16x16x32_bf16(xl, wh1, acc1, 0, 0, 0);
        acc1 = __builtin_amdgcn_mfma_f32_16x16x32_bf16(xh, wl1, acc1, 0, 0, 0);
    }

    // t1/t2 partials + LDS combine (pre-scaled by log2e)
    {
        float a10 = a1[(2 * wv) * 16 + lr], a11 = a1[(2 * wv + 1) * 16 + lr];
        float a20 = a2[(2 * wv) * 16 + lr], a21 = a2[(2 * wv + 1) * 16 + lr];
        float p1[4], p2[4];
#pragma unroll
        for (int r = 0; r < 4; r++) {
            p1[r] = acc0[r] * a10 + acc1[r] * a11;
            p2[r] = acc0[r] * a20 + acc1[r] * a21;
        }
#pragma unroll
        for (int off = 1; off < 16; off <<= 1) {
#pragma unroll
            for (int r = 0; r < 4; r++) {
                p1[r] += __shfl_xor(p1[r], off);
                p2[r] += __shfl_xor(p2[r], off);
            }
        }
        if (lr == 0) {
#pragma unroll
            for (int r = 0; r < 4; r++) {
                lds_t1[wv][lg * 4 + r] = p1[r];
                lds_t2[wv][lg * 4 + r] = p2[r];
            }
        }
        __syncthreads();
        if (tid < 16) {
            t1[row0 + tid] = (lds_t1[0][tid] + lds_t1[1][tid] + lds_t1[2][tid] + lds_t1[3][tid]) * LOG2E;
            t2[row0 + tid] = (lds_t2[0][tid] + lds_t2[1][tid] + lds_t2[2][tid] + lds_t2[3][tid]) * LOG2E;
        }
    }

    // repack h -> B-fragment layout via intra-wave shuffles
    {
        size_t jtg = (size_t)(blk >> 1);
        int srcbase = (2 * (lg & 1)) * 16 + lr;
        bool active = (lg >> 1) == (blk & 1);
#pragma unroll
        for (int t = 0; t < 2; t++) {
            f32x4 a = t == 0 ? acc0 : acc1;
            unsigned p0 = cvt_pk_bf16(a[0], a[1]);
            unsigned p1 = cvt_pk_bf16(a[2], a[3]);
            unsigned g0 = __shfl((int)p0, srcbase);
            unsigned g1 = __shfl((int)p1, srcbase);
            unsigned g2 = __shfl((int)p0, srcbase + 16);
            unsigned g3 = __shfl((int)p1, srcbase + 16);
            if (active) {
                uint4 v = {g0, g1, g2, g3};
                int t_o = 2 * wv + t;
                *(uint4*)(hb + (jtg * 8 + t_o) * 512 + l * 8) = v;
            }
        }
    }
}

// ---------------- Kernel B: fused masked-softmax attention + PV (MFMA) ----------------
// grid = B*N/16 = 512 blocks, 512 threads (8 waves).
// Wave wv handles j-tiles jt = wv + 8*it (it=0..7, fully unrolled), all 8 o-tiles.
// Mask bits prefetched into registers before the loop. No online max (logits bounded;
// masked -> p=0 exactly). Cross-wave combine = pure sum, two-phase LDS.
__global__ void __launch_bounds__(512, 4) k_attn(const unsigned* __restrict__ maskw,
                                                 const float* __restrict__ t1g,
                                                 const float* __restrict__ t2g,
                                                 const unsigned short* __restrict__ hb,
                                                 float* __restrict__ out) {
    __shared__ __align__(16) float accbuf[4][16][132];   // 33792 B
    __shared__ float lds_s[8][16];
    __shared__ float lds_inv[16];

    int blk = blockIdx.x;
    int b = blk >> 7;
    int i0 = (blk & 127) * 16;
    int tid = threadIdx.x;
    int wv = tid >> 6;            // 0..7
    int l = tid & 63;
    int lr = l & 15, lg = l >> 4;

    float t1v = t1g[b * NN + i0 + lr];                       // pre-scaled by log2e
    const float* t2p = t2g + b * NN + lg * 8;                // pre-scaled by log2e
    const unsigned short* hbbase = hb + (size_t)b * 64 * 4096 + (size_t)l * 8;
    const unsigned* mrow = maskw + (size_t)b * 64 * NN + (i0 + lr);

    // prefetch all 8 mask words for this wave's tiles (stay in VGPRs: loop fully unrolled)
    unsigned mwv[8];
#pragma unroll
    for (int it = 0; it < 8; it++)
        mwv[it] = mrow[(size_t)(wv + it * 8) * NN];

    float s = 0.f;
    f32x4 acc[8];
#pragma unroll
    for (int t = 0; t < 8; t++) acc[t] = (f32x4){0.f, 0.f, 0.f, 0.f};

#pragma unroll
    for (int it = 0; it < 8; it++) {
        int jt = wv + it * 8;
        float4 tb0 = *(const float4*)(t2p + jt * 32);
        float4 tb1 = *(const float4*)(t2p + jt * 32 + 4);
        bf16x8 hf[8];
#pragma unroll
        for (int t = 0; t < 8; t++)
            hf[t] = *(const bf16x8*)(hbbase + (size_t)jt * 4096 + t * 512);

        unsigned mbyte = mwv[it] >> (lg * 8);
        float tv[8] = {tb0.x, tb0.y, tb0.z, tb0.w, tb1.x, tb1.y, tb1.z, tb1.w};
        float p[8];
        float psum = 0.f;
#pragma unroll
        for (int jj = 0; jj < 8; jj++) {
            float v = t1v + tv[jj];
            float e = fmaxf(v, ALPHAV * v);              // leaky relu (log2 domain)
            float ex = __builtin_amdgcn_exp2f(e);
            p[jj] = (mbyte & (1u << jj)) ? ex : 0.f;
            psum += p[jj];
        }
        s += psum;

        unsigned u[4];
#pragma unroll
        for (int w = 0; w < 4; w++) u[w] = cvt_pk_bf16(p[2 * w], p[2 * w + 1]);
        bf16x8 pa = *(const bf16x8*)u;
#pragma unroll
        for (int t = 0; t < 8; t++)
            acc[t] = __builtin_amdgcn_mfma_f32_16x16x32_bf16(pa, hf[t], acc[t], 0, 0, 0);
    }

    // ---- cross-wave sum combine ----
    s += __shfl_xor(s, 16);
    s += __shfl_xor(s, 32);
    if (l < 16) lds_s[wv][lr] = s;

    if (wv < 4) {
#pragma unroll
        for (int t = 0; t < 8; t++)
#pragma unroll
            for (int r = 0; r < 4; r++)
                accbuf[wv][lg * 4 + r][t * 16 + lr] = acc[t][r];
    }
    __syncthreads();
    if (wv >= 4) {
#pragma unroll
        for (int t = 0; t < 8; t++)
#pragma unroll
            for (int r = 0; r < 4; r++)
                accbuf[wv - 4][lg * 4 + r][t * 16 + lr] += acc[t][r];
    }
    if (tid < 16) {
        float st = 0.f;
#pragma unroll
        for (int w = 0; w < 8; w++) st += lds_s[w][tid];
        lds_inv[tid] = 1.0f / st;
    }
    __syncthreads();

    // ---- final: 512 threads x 1 float4 = 16x128 outputs ----
    {
        int row = tid >> 5;
        int c4 = (tid & 31) * 4;
        float4 s0 = *(const float4*)&accbuf[0][row][c4];
        float4 s1 = *(const float4*)&accbuf[1][row][c4];
        float4 s2 = *(const float4*)&accbuf[2][row][c4];
        float4 s3 = *(const float4*)&accbuf[3][row][c4];
        float inv = lds_inv[row];
        float4 o;
        o.x = (s0.x + s1.x + s2.x + s3.x) * inv;
        o.y = (s0.y + s1.y + s2.y + s3.y) * inv;
        o.z = (s0.z + s1.z + s2.z + s3.z) * inv;
        o.w = (s0.w + s1.w + s2.w + s3.w) * inv;
        *(float4*)&out[((size_t)b * NN + i0 + row) * FOUT + c4] = o;
    }
}

extern "C" void kernel_launch(void* const* d_in, const int* in_sizes, int n_in,
                              void* d_out, int out_size, void* d_ws, size_t ws_size,
                              hipStream_t stream) {
    const float* x  = (const float*)d_in[0];
    const float* W  = (const float*)d_in[1];
    const float* a1 = (const float*)d_in[2];
    const float* a2 = (const float*)d_in[3];
    const int* adj  = (const int*)d_in[4];
    // d_in[5] = adj_tree (unused by reference forward)
    const int* d1p  = (const int*)d_in[6];
    const int* d2p  = (const int*)d_in[7];
    float* out = (float*)d_out;

    char* ws = (char*)d_ws;
    unsigned short* hbuf = (unsigned short*)(ws);                       // 2 MB
    float* t1            = (float*)(ws + 2u * 1024 * 1024);             // 32 KB
    float* t2            = (float*)(ws + 2u * 1024 * 1024 + 32 * 1024); // 32 KB
    unsigned short* whi  = (unsigned short*)(ws + 2u * 1024 * 1024 + 64 * 1024);  // 128 KB
    unsigned short* wlo  = (unsigned short*)(ws + 2u * 1024 * 1024 + 192 * 1024); // 128 KB
    unsigned* maskw      = (unsigned*)(ws + 2u * 1024 * 1024 + 320 * 1024);       // 2 MB

    k_wrep<<<dim3(128), dim3(64), 0, stream>>>(W, whi, wlo);
    k_prep<<<dim3(2560), dim3(256), 0, stream>>>(x, whi, wlo, a1, a2, adj, d1p, d2p,
                                                 hbuf, t1, t2, maskw);
    k_attn<<<dim3(512), dim3(512), 0, stream>>>(maskw, t1, t2, hbuf, out);
}

// Round 7
// 56.417 us; speedup vs baseline: 1.2343x; 1.2343x over previous
//
#include <hip/hip_runtime.h>
#include <hip/hip_bf16.h>

#define NN 2048
#define FIN 512
#define FOUT 128
#define ALPHAV 0.2f
#define LOG2E 1.44269504088896340736f

typedef __attribute__((ext_vector_type(8))) short bf16x8;
typedef __attribute__((ext_vector_type(4))) float f32x4;

__device__ __forceinline__ unsigned cvt_pk_bf16(float lo, float hi) {
    unsigned r;
    asm("v_cvt_pk_bf16_f32 %0, %1, %2" : "=v"(r) : "v"(lo), "v"(hi));
    return r;   // low16 = bf16(lo), high16 = bf16(hi), RNE
}

__device__ __forceinline__ unsigned short f32_to_bf16(float f) {
    unsigned int u = __float_as_uint(f);
    unsigned int r = (u + 0x7FFFu + ((u >> 16) & 1u)) >> 16;   // RNE
    return (unsigned short)r;
}

// ---------------- Kernel W: repack W -> bf16 hi/lo MFMA-B fragments ----------------
__global__ void k_wrep(const float* __restrict__ W,
                       unsigned short* __restrict__ whi,
                       unsigned short* __restrict__ wlo) {
    int kt = blockIdx.x >> 3;
    int t_o = blockIdx.x & 7;
    int l = threadIdx.x;
    int lr = l & 15, lg = l >> 4;
    unsigned short vh[8], vl[8];
#pragma unroll
    for (int jj = 0; jj < 8; jj++) {
        float f = W[(size_t)(kt * 32 + lg * 8 + jj) * FOUT + t_o * 16 + lr];
        unsigned short h = f32_to_bf16(f);
        float hf = __uint_as_float(((unsigned)h) << 16);
        vh[jj] = h;
        vl[jj] = f32_to_bf16(f - hf);
    }
    size_t o = ((size_t)(kt * 8 + t_o) * 64 + l) * 8;
    *(uint4*)(whi + o) = *(const uint4*)vh;
    *(uint4*)(wlo + o) = *(const uint4*)vl;
}

// ---------------- Kernel P: fused {adj->byte-mask stream} + {h=x@W MFMA, t1/t2, repack} ----------------
// grid = 2048 (mask) + 512 (h) blocks, 256 threads.
// Mask path: block = 4 rows (one per wave). Per iter, lane reads 8 contiguous ints
// (2 KB/wave contiguous), emits 1 byte: maskb[row*256 + j/8] bit (j%8) = (adj==d1||==d2).
// No cross-lane ops, no divergence -> streams at HBM BW.
// H path: 16 rows x 128 cols split-bf16 MFMA; t1/t2 pre-scaled by log2(e).
__global__ void __launch_bounds__(256) k_prep(const float* __restrict__ x,
                                              const unsigned short* __restrict__ whi,
                                              const unsigned short* __restrict__ wlo,
                                              const float* __restrict__ a1,
                                              const float* __restrict__ a2,
                                              const int* __restrict__ adj,
                                              const int* __restrict__ d1p,
                                              const int* __restrict__ d2p,
                                              unsigned short* __restrict__ hb,
                                              float* __restrict__ t1,
                                              float* __restrict__ t2,
                                              unsigned char* __restrict__ maskb) {
    __shared__ float lds_t1[4][16];
    __shared__ float lds_t2[4][16];
    int tid = threadIdx.x;
    int wv = tid >> 6, l = tid & 63;
    int lr = l & 15, lg = l >> 4;

    if (blockIdx.x < 2048) {
        // ---------- mask compression path (BW-bound streaming) ----------
        int d1 = d1p[0], d2 = d2p[0];
        int row = blockIdx.x * 4 + wv;                    // b*2048 + i
        const int4* ap = (const int4*)(adj + (size_t)row * NN);
        unsigned char* mp = maskb + (size_t)row * 256;
#pragma unroll
        for (int it = 0; it < 4; it++) {
            int4 v0 = ap[it * 128 + l * 2];
            int4 v1 = ap[it * 128 + l * 2 + 1];
            unsigned by = 0;
            by |= (v0.x == d1 || v0.x == d2) ? 1u : 0u;
            by |= (v0.y == d1 || v0.y == d2) ? 2u : 0u;
            by |= (v0.z == d1 || v0.z == d2) ? 4u : 0u;
            by |= (v0.w == d1 || v0.w == d2) ? 8u : 0u;
            by |= (v1.x == d1 || v1.x == d2) ? 16u : 0u;
            by |= (v1.y == d1 || v1.y == d2) ? 32u : 0u;
            by |= (v1.z == d1 || v1.z == d2) ? 64u : 0u;
            by |= (v1.w == d1 || v1.w == d2) ? 128u : 0u;
            mp[it * 64 + l] = (unsigned char)by;
        }
        return;
    }

    // ---------- h path ----------
    int blk = blockIdx.x - 2048;
    int row0 = blk * 16;

    const float* xp = x + (size_t)(row0 + lr) * FIN + lg * 8;
    const unsigned short* wb = whi + (size_t)(2 * wv) * 512 + l * 8;
    const unsigned short* lb = wlo + (size_t)(2 * wv) * 512 + l * 8;

    f32x4 acc0 = {0.f, 0.f, 0.f, 0.f};
    f32x4 acc1 = {0.f, 0.f, 0.f, 0.f};

#pragma unroll 2
    for (int kt = 0; kt < FIN / 32; kt++) {
        float4 xa = *(const float4*)(xp + kt * 32);
        float4 xb = *(const float4*)(xp + kt * 32 + 4);
        bf16x8 wh0 = *(const bf16x8*)(wb + (size_t)kt * 4096);
        bf16x8 wh1 = *(const bf16x8*)(wb + (size_t)kt * 4096 + 512);
        bf16x8 wl0 = *(const bf16x8*)(lb + (size_t)kt * 4096);
        bf16x8 wl1 = *(const bf16x8*)(lb + (size_t)kt * 4096 + 512);

        float f[8] = {xa.x, xa.y, xa.z, xa.w, xb.x, xb.y, xb.z, xb.w};
        unsigned uh[4], ul[4];
#pragma unroll
        for (int w = 0; w < 4; w++) {
            uh[w] = cvt_pk_bf16(f[2 * w], f[2 * w + 1]);
            float r0 = f[2 * w]     - __uint_as_float(uh[w] << 16);
            float r1 = f[2 * w + 1] - __uint_as_float(uh[w] & 0xffff0000u);
            ul[w] = cvt_pk_bf16(r0, r1);
        }
        bf16x8 xh = *(const bf16x8*)uh;
        bf16x8 xl = *(const bf16x8*)ul;

        acc0 = __builtin_amdgcn_mfma_f32_16x16x32_bf16(xh, wh0, acc0, 0, 0, 0);
        acc0 = __builtin_amdgcn_mfma_f32_16x16x32_bf16(xl, wh0, acc0, 0, 0, 0);
        acc0 = __builtin_amdgcn_mfma_f32_16x16x32_bf16(xh, wl0, acc0, 0, 0, 0);
        acc1 = __builtin_amdgcn_mfma_f32_16x16x32_bf16(xh, wh1, acc1, 0, 0, 0);
        acc1 = __builtin_amdgcn_mfma_f32_16x16x32_bf16(xl, wh1, acc1, 0, 0, 0);
        acc1 = __builtin_amdgcn_mfma_f32_16x16x32_bf16(xh, wl1, acc1, 0, 0, 0);
    }

    // t1/t2 partials + LDS combine (pre-scaled by log2e)
    {
        float a10 = a1[(2 * wv) * 16 + lr], a11 = a1[(2 * wv + 1) * 16 + lr];
        float a20 = a2[(2 * wv) * 16 + lr], a21 = a2[(2 * wv + 1) * 16 + lr];
        float p1[4], p2[4];
#pragma unroll
        for (int r = 0; r < 4; r++) {
            p1[r] = acc0[r] * a10 + acc1[r] * a11;
            p2[r] = acc0[r] * a20 + acc1[r] * a21;
        }
#pragma unroll
        for (int off = 1; off < 16; off <<= 1) {
#pragma unroll
            for (int r = 0; r < 4; r++) {
                p1[r] += __shfl_xor(p1[r], off);
                p2[r] += __shfl_xor(p2[r], off);
            }
        }
        if (lr == 0) {
#pragma unroll
            for (int r = 0; r < 4; r++) {
                lds_t1[wv][lg * 4 + r] = p1[r];
                lds_t2[wv][lg * 4 + r] = p2[r];
            }
        }
        __syncthreads();
        if (tid < 16) {
            t1[row0 + tid] = (lds_t1[0][tid] + lds_t1[1][tid] + lds_t1[2][tid] + lds_t1[3][tid]) * LOG2E;
            t2[row0 + tid] = (lds_t2[0][tid] + lds_t2[1][tid] + lds_t2[2][tid] + lds_t2[3][tid]) * LOG2E;
        }
    }

    // repack h -> B-fragment layout via intra-wave shuffles
    {
        size_t jtg = (size_t)(blk >> 1);
        int srcbase = (2 * (lg & 1)) * 16 + lr;
        bool active = (lg >> 1) == (blk & 1);
#pragma unroll
        for (int t = 0; t < 2; t++) {
            f32x4 a = t == 0 ? acc0 : acc1;
            unsigned p0 = cvt_pk_bf16(a[0], a[1]);
            unsigned p1 = cvt_pk_bf16(a[2], a[3]);
            unsigned g0 = __shfl((int)p0, srcbase);
            unsigned g1 = __shfl((int)p1, srcbase);
            unsigned g2 = __shfl((int)p0, srcbase + 16);
            unsigned g3 = __shfl((int)p1, srcbase + 16);
            if (active) {
                uint4 v = {g0, g1, g2, g3};
                int t_o = 2 * wv + t;
                *(uint4*)(hb + (jtg * 8 + t_o) * 512 + l * 8) = v;
            }
        }
    }
}

// ---------------- Kernel B: fused masked-softmax attention + PV (MFMA) ----------------
// grid = B*N/16 = 512 blocks, 512 threads (8 waves).
// Wave wv handles j-tiles jt = wv + 8*it (it=0..7, fully unrolled), all 8 o-tiles.
// Mask bytes prefetched into registers. No online max (logits bounded in log2 domain;
// masked -> p=0 exactly). Cross-wave combine = pure sum, two-phase LDS.
__global__ void __launch_bounds__(512, 4) k_attn(const unsigned char* __restrict__ maskb,
                                                 const float* __restrict__ t1g,
                                                 const float* __restrict__ t2g,
                                                 const unsigned short* __restrict__ hb,
                                                 float* __restrict__ out) {
    __shared__ __align__(16) float accbuf[4][16][132];   // 33792 B
    __shared__ float lds_s[8][16];
    __shared__ float lds_inv[16];

    int blk = blockIdx.x;
    int b = blk >> 7;
    int i0 = (blk & 127) * 16;
    int tid = threadIdx.x;
    int wv = tid >> 6;            // 0..7
    int l = tid & 63;
    int lr = l & 15, lg = l >> 4;

    float t1v = t1g[b * NN + i0 + lr];                       // pre-scaled by log2e
    const float* t2p = t2g + b * NN + lg * 8;                // pre-scaled by log2e
    const unsigned short* hbbase = hb + (size_t)b * 64 * 4096 + (size_t)l * 8;
    // mask byte for (row = i0+lr, jt): maskb[row*256 + jt*4 + lg]
    const unsigned char* mrow = maskb + (size_t)(b * NN + i0 + lr) * 256 + lg;

    // prefetch all 8 mask bytes for this wave's tiles (loop fully unrolled -> VGPRs)
    unsigned mby[8];
#pragma unroll
    for (int it = 0; it < 8; it++)
        mby[it] = mrow[(wv + it * 8) * 4];

    float s = 0.f;
    f32x4 acc[8];
#pragma unroll
    for (int t = 0; t < 8; t++) acc[t] = (f32x4){0.f, 0.f, 0.f, 0.f};

#pragma unroll
    for (int it = 0; it < 8; it++) {
        int jt = wv + it * 8;
        float4 tb0 = *(const float4*)(t2p + jt * 32);
        float4 tb1 = *(const float4*)(t2p + jt * 32 + 4);
        bf16x8 hf[8];
#pragma unroll
        for (int t = 0; t < 8; t++)
            hf[t] = *(const bf16x8*)(hbbase + (size_t)jt * 4096 + t * 512);

        unsigned mbyte = mby[it];
        float tv[8] = {tb0.x, tb0.y, tb0.z, tb0.w, tb1.x, tb1.y, tb1.z, tb1.w};
        float p[8];
        float psum = 0.f;
#pragma unroll
        for (int jj = 0; jj < 8; jj++) {
            float v = t1v + tv[jj];
            float e = fmaxf(v, ALPHAV * v);              // leaky relu (log2 domain)
            float ex = __builtin_amdgcn_exp2f(e);
            p[jj] = (mbyte & (1u << jj)) ? ex : 0.f;
            psum += p[jj];
        }
        s += psum;

        unsigned u[4];
#pragma unroll
        for (int w = 0; w < 4; w++) u[w] = cvt_pk_bf16(p[2 * w], p[2 * w + 1]);
        bf16x8 pa = *(const bf16x8*)u;
#pragma unroll
        for (int t = 0; t < 8; t++)
            acc[t] = __builtin_amdgcn_mfma_f32_16x16x32_bf16(pa, hf[t], acc[t], 0, 0, 0);
    }

    // ---- cross-wave sum combine ----
    s += __shfl_xor(s, 16);
    s += __shfl_xor(s, 32);
    if (l < 16) lds_s[wv][lr] = s;

    if (wv < 4) {
#pragma unroll
        for (int t = 0; t < 8; t++)
#pragma unroll
            for (int r = 0; r < 4; r++)
                accbuf[wv][lg * 4 + r][t * 16 + lr] = acc[t][r];
    }
    __syncthreads();
    if (wv >= 4) {
#pragma unroll
        for (int t = 0; t < 8; t++)
#pragma unroll
            for (int r = 0; r < 4; r++)
                accbuf[wv - 4][lg * 4 + r][t * 16 + lr] += acc[t][r];
    }
    if (tid < 16) {
        float st = 0.f;
#pragma unroll
        for (int w = 0; w < 8; w++) st += lds_s[w][tid];
        lds_inv[tid] = 1.0f / st;
    }
    __syncthreads();

    // ---- final: 512 threads x 1 float4 = 16x128 outputs ----
    {
        int row = tid >> 5;
        int c4 = (tid & 31) * 4;
        float4 s0 = *(const float4*)&accbuf[0][row][c4];
        float4 s1 = *(const float4*)&accbuf[1][row][c4];
        float4 s2 = *(const float4*)&accbuf[2][row][c4];
        float4 s3 = *(const float4*)&accbuf[3][row][c4];
        float inv = lds_inv[row];
        float4 o;
        o.x = (s0.x + s1.x + s2.x + s3.x) * inv;
        o.y = (s0.y + s1.y + s2.y + s3.y) * inv;
        o.z = (s0.z + s1.z + s2.z + s3.z) * inv;
        o.w = (s0.w + s1.w + s2.w + s3.w) * inv;
        *(float4*)&out[((size_t)b * NN + i0 + row) * FOUT + c4] = o;
    }
}

extern "C" void kernel_launch(void* const* d_in, const int* in_sizes, int n_in,
                              void* d_out, int out_size, void* d_ws, size_t ws_size,
                              hipStream_t stream) {
    const float* x  = (const float*)d_in[0];
    const float* W  = (const float*)d_in[1];
    const float* a1 = (const float*)d_in[2];
    const float* a2 = (const float*)d_in[3];
    const int* adj  = (const int*)d_in[4];
    // d_in[5] = adj_tree (unused by reference forward)
    const int* d1p  = (const int*)d_in[6];
    const int* d2p  = (const int*)d_in[7];
    float* out = (float*)d_out;

    char* ws = (char*)d_ws;
    unsigned short* hbuf = (unsigned short*)(ws);                       // 2 MB
    float* t1            = (float*)(ws + 2u * 1024 * 1024);             // 32 KB
    float* t2            = (float*)(ws + 2u * 1024 * 1024 + 32 * 1024); // 32 KB
    unsigned short* whi  = (unsigned short*)(ws + 2u * 1024 * 1024 + 64 * 1024);  // 128 KB
    unsigned short* wlo  = (unsigned short*)(ws + 2u * 1024 * 1024 + 192 * 1024); // 128 KB
    unsigned char* maskb = (unsigned char*)(ws + 2u * 1024 * 1024 + 320 * 1024);  // 2 MB

    k_wrep<<<dim3(128), dim3(64), 0, stream>>>(W, whi, wlo);
    k_prep<<<dim3(2560), dim3(256), 0, stream>>>(x, whi, wlo, a1, a2, adj, d1p, d2p,
                                                 hbuf, t1, t2, maskb);
    k_attn<<<dim3(512), dim3(512), 0, stream>>>(maskb, t1, t2, hbuf, out);
}

// Round 8
// 48.376 us; speedup vs baseline: 1.4395x; 1.1662x over previous
//
#include <hip/hip_runtime.h>
#include <hip/hip_bf16.h>

#define NN 2048
#define FIN 512
#define FOUT 128
#define ALPHAV 0.2f
#define LOG2E 1.44269504088896340736f

typedef __attribute__((ext_vector_type(8))) short bf16x8;
typedef __attribute__((ext_vector_type(4))) float f32x4;

__device__ __forceinline__ unsigned cvt_pk_bf16(float lo, float hi) {
    unsigned r;
    asm("v_cvt_pk_bf16_f32 %0, %1, %2" : "=v"(r) : "v"(lo), "v"(hi));
    return r;   // low16 = bf16(lo), high16 = bf16(hi), RNE
}

__device__ __forceinline__ unsigned short f32_to_bf16(float f) {
    unsigned int u = __float_as_uint(f);
    unsigned int r = (u + 0x7FFFu + ((u >> 16) & 1u)) >> 16;   // RNE
    return (unsigned short)r;
}

// ---------------- Kernel S: {adj -> byte-mask} stream + W-repack tail ----------------
// grid = 2048 (mask) + 32 (wrep) blocks, 256 threads. No MFMA, low VGPR -> full ILP/TLP.
// Mask: block = 4 rows (one per wave); lane reads 8 contiguous ints (2x int4),
//   emits 1 byte: maskb[row*256 + j/8] bit (j%8) = (adj==d1 || adj==d2).
// Wrep: whi/wlo[(kt*8+t_o)*512 + l*8 + jj] = bf16_hi/lo(W[kt*32+(l>>4)*8+jj][t_o*16+(l&15)])
__global__ void __launch_bounds__(256) k_stream(const int* __restrict__ adj,
                                                const int* __restrict__ d1p,
                                                const int* __restrict__ d2p,
                                                const float* __restrict__ W,
                                                unsigned char* __restrict__ maskb,
                                                unsigned short* __restrict__ whi,
                                                unsigned short* __restrict__ wlo) {
    int tid = threadIdx.x;
    int wv = tid >> 6, l = tid & 63;

    if (blockIdx.x < 2048) {
        int d1 = d1p[0], d2 = d2p[0];
        int row = blockIdx.x * 4 + wv;                    // b*2048 + i
        const int4* ap = (const int4*)(adj + (size_t)row * NN);
        unsigned char* mp = maskb + (size_t)row * 256;
#pragma unroll
        for (int it = 0; it < 4; it++) {
            int4 v0 = ap[it * 128 + l * 2];
            int4 v1 = ap[it * 128 + l * 2 + 1];
            unsigned by = 0;
            by |= (v0.x == d1 || v0.x == d2) ? 1u : 0u;
            by |= (v0.y == d1 || v0.y == d2) ? 2u : 0u;
            by |= (v0.z == d1 || v0.z == d2) ? 4u : 0u;
            by |= (v0.w == d1 || v0.w == d2) ? 8u : 0u;
            by |= (v1.x == d1 || v1.x == d2) ? 16u : 0u;
            by |= (v1.y == d1 || v1.y == d2) ? 32u : 0u;
            by |= (v1.z == d1 || v1.z == d2) ? 64u : 0u;
            by |= (v1.w == d1 || v1.w == d2) ? 128u : 0u;
            mp[it * 64 + l] = (unsigned char)by;
        }
        return;
    }

    // ---- W repack tail: 32 blocks x 4 subunits = 128 (kt,t_o) tiles ----
    {
        int idx = (blockIdx.x - 2048) * 4 + wv;
        int kt = idx >> 3;
        int t_o = idx & 7;
        int lr = l & 15, lg = l >> 4;
        unsigned short vh[8], vl[8];
#pragma unroll
        for (int jj = 0; jj < 8; jj++) {
            float f = W[(size_t)(kt * 32 + lg * 8 + jj) * FOUT + t_o * 16 + lr];
            unsigned short h = f32_to_bf16(f);
            float hf = __uint_as_float(((unsigned)h) << 16);
            vh[jj] = h;
            vl[jj] = f32_to_bf16(f - hf);
        }
        size_t o = ((size_t)(kt * 8 + t_o) * 64 + l) * 8;
        *(uint4*)(whi + o) = *(const uint4*)vh;
        *(uint4*)(wlo + o) = *(const uint4*)vl;
    }
}

// ---------------- Kernel H: h = x@W via split-bf16 MFMA; t1/t2; frag repack ----------------
// grid = 8192/16 = 512 blocks, 256 threads (4 waves).
// Block owns 16 rows x 128 cols; wave wv owns o-tiles {2wv, 2wv+1}.
// t1/t2 stored PRE-SCALED by log2(e) for k_attn's exp2.
__global__ void __launch_bounds__(256) k_h(const float* __restrict__ x,
                                           const unsigned short* __restrict__ whi,
                                           const unsigned short* __restrict__ wlo,
                                           const float* __restrict__ a1,
                                           const float* __restrict__ a2,
                                           unsigned short* __restrict__ hb,
                                           float* __restrict__ t1,
                                           float* __restrict__ t2) {
    __shared__ float lds_t1[4][16];
    __shared__ float lds_t2[4][16];
    int blk = blockIdx.x;
    int tid = threadIdx.x;
    int wv = tid >> 6, l = tid & 63;
    int lr = l & 15, lg = l >> 4;
    int row0 = blk * 16;

    const float* xp = x + (size_t)(row0 + lr) * FIN + lg * 8;
    const unsigned short* wb = whi + (size_t)(2 * wv) * 512 + l * 8;
    const unsigned short* lb = wlo + (size_t)(2 * wv) * 512 + l * 8;

    f32x4 acc0 = {0.f, 0.f, 0.f, 0.f};
    f32x4 acc1 = {0.f, 0.f, 0.f, 0.f};

#pragma unroll 2
    for (int kt = 0; kt < FIN / 32; kt++) {
        float4 xa = *(const float4*)(xp + kt * 32);
        float4 xb = *(const float4*)(xp + kt * 32 + 4);
        bf16x8 wh0 = *(const bf16x8*)(wb + (size_t)kt * 4096);
        bf16x8 wh1 = *(const bf16x8*)(wb + (size_t)kt * 4096 + 512);
        bf16x8 wl0 = *(const bf16x8*)(lb + (size_t)kt * 4096);
        bf16x8 wl1 = *(const bf16x8*)(lb + (size_t)kt * 4096 + 512);

        float f[8] = {xa.x, xa.y, xa.z, xa.w, xb.x, xb.y, xb.z, xb.w};
        unsigned uh[4], ul[4];
#pragma unroll
        for (int w = 0; w < 4; w++) {
            uh[w] = cvt_pk_bf16(f[2 * w], f[2 * w + 1]);
            float r0 = f[2 * w]     - __uint_as_float(uh[w] << 16);
            float r1 = f[2 * w + 1] - __uint_as_float(uh[w] & 0xffff0000u);
            ul[w] = cvt_pk_bf16(r0, r1);
        }
        bf16x8 xh = *(const bf16x8*)uh;
        bf16x8 xl = *(const bf16x8*)ul;

        acc0 = __builtin_amdgcn_mfma_f32_16x16x32_bf16(xh, wh0, acc0, 0, 0, 0);
        acc0 = __builtin_amdgcn_mfma_f32_16x16x32_bf16(xl, wh0, acc0, 0, 0, 0);
        acc0 = __builtin_amdgcn_mfma_f32_16x16x32_bf16(xh, wl0, acc0, 0, 0, 0);
        acc1 = __builtin_amdgcn_mfma_f32_16x16x32_bf16(xh, wh1, acc1, 0, 0, 0);
        acc1 = __builtin_amdgcn_mfma_f32_16x16x32_bf16(xl, wh1, acc1, 0, 0, 0);
        acc1 = __builtin_amdgcn_mfma_f32_16x16x32_bf16(xh, wl1, acc1, 0, 0, 0);
    }

    // t1/t2 partials + LDS combine (pre-scaled by log2e)
    {
        float a10 = a1[(2 * wv) * 16 + lr], a11 = a1[(2 * wv + 1) * 16 + lr];
        float a20 = a2[(2 * wv) * 16 + lr], a21 = a2[(2 * wv + 1) * 16 + lr];
        float p1[4], p2[4];
#pragma unroll
        for (int r = 0; r < 4; r++) {
            p1[r] = acc0[r] * a10 + acc1[r] * a11;
            p2[r] = acc0[r] * a20 + acc1[r] * a21;
        }
#pragma unroll
        for (int off = 1; off < 16; off <<= 1) {
#pragma unroll
            for (int r = 0; r < 4; r++) {
                p1[r] += __shfl_xor(p1[r], off);
                p2[r] += __shfl_xor(p2[r], off);
            }
        }
        if (lr == 0) {
#pragma unroll
            for (int r = 0; r < 4; r++) {
                lds_t1[wv][lg * 4 + r] = p1[r];
                lds_t2[wv][lg * 4 + r] = p2[r];
            }
        }
        __syncthreads();
        if (tid < 16) {
            t1[row0 + tid] = (lds_t1[0][tid] + lds_t1[1][tid] + lds_t1[2][tid] + lds_t1[3][tid]) * LOG2E;
            t2[row0 + tid] = (lds_t2[0][tid] + lds_t2[1][tid] + lds_t2[2][tid] + lds_t2[3][tid]) * LOG2E;
        }
    }

    // repack h -> B-fragment layout via intra-wave shuffles
    {
        size_t jtg = (size_t)(blk >> 1);
        int srcbase = (2 * (lg & 1)) * 16 + lr;
        bool active = (lg >> 1) == (blk & 1);
#pragma unroll
        for (int t = 0; t < 2; t++) {
            f32x4 a = t == 0 ? acc0 : acc1;
            unsigned p0 = cvt_pk_bf16(a[0], a[1]);
            unsigned p1 = cvt_pk_bf16(a[2], a[3]);
            unsigned g0 = __shfl((int)p0, srcbase);
            unsigned g1 = __shfl((int)p1, srcbase);
            unsigned g2 = __shfl((int)p0, srcbase + 16);
            unsigned g3 = __shfl((int)p1, srcbase + 16);
            if (active) {
                uint4 v = {g0, g1, g2, g3};
                int t_o = 2 * wv + t;
                *(uint4*)(hb + (jtg * 8 + t_o) * 512 + l * 8) = v;
            }
        }
    }
}

// ---------------- Kernel B: fused masked-softmax attention + PV (MFMA) ----------------
// grid = B*N/16 = 512 blocks, 512 threads (8 waves).
// Wave wv handles j-tiles jt = wv + 8*it (it=0..7, fully unrolled), all 8 o-tiles.
// Mask bytes prefetched into registers. No online max (logits bounded in log2 domain;
// masked -> p=0 exactly). Cross-wave combine = pure sum, two-phase LDS.
__global__ void __launch_bounds__(512, 4) k_attn(const unsigned char* __restrict__ maskb,
                                                 const float* __restrict__ t1g,
                                                 const float* __restrict__ t2g,
                                                 const unsigned short* __restrict__ hb,
                                                 float* __restrict__ out) {
    __shared__ __align__(16) float accbuf[4][16][132];   // 33792 B
    __shared__ float lds_s[8][16];
    __shared__ float lds_inv[16];

    int blk = blockIdx.x;
    int b = blk >> 7;
    int i0 = (blk & 127) * 16;
    int tid = threadIdx.x;
    int wv = tid >> 6;            // 0..7
    int l = tid & 63;
    int lr = l & 15, lg = l >> 4;

    float t1v = t1g[b * NN + i0 + lr];                       // pre-scaled by log2e
    const float* t2p = t2g + b * NN + lg * 8;                // pre-scaled by log2e
    const unsigned short* hbbase = hb + (size_t)b * 64 * 4096 + (size_t)l * 8;
    const unsigned char* mrow = maskb + (size_t)(b * NN + i0 + lr) * 256 + lg;

    unsigned mby[8];
#pragma unroll
    for (int it = 0; it < 8; it++)
        mby[it] = mrow[(wv + it * 8) * 4];

    float s = 0.f;
    f32x4 acc[8];
#pragma unroll
    for (int t = 0; t < 8; t++) acc[t] = (f32x4){0.f, 0.f, 0.f, 0.f};

#pragma unroll
    for (int it = 0; it < 8; it++) {
        int jt = wv + it * 8;
        float4 tb0 = *(const float4*)(t2p + jt * 32);
        float4 tb1 = *(const float4*)(t2p + jt * 32 + 4);
        bf16x8 hf[8];
#pragma unroll
        for (int t = 0; t < 8; t++)
            hf[t] = *(const bf16x8*)(hbbase + (size_t)jt * 4096 + t * 512);

        unsigned mbyte = mby[it];
        float tv[8] = {tb0.x, tb0.y, tb0.z, tb0.w, tb1.x, tb1.y, tb1.z, tb1.w};
        float p[8];
        float psum = 0.f;
#pragma unroll
        for (int jj = 0; jj < 8; jj++) {
            float v = t1v + tv[jj];
            float e = fmaxf(v, ALPHAV * v);              // leaky relu (log2 domain)
            float ex = __builtin_amdgcn_exp2f(e);
            p[jj] = (mbyte & (1u << jj)) ? ex : 0.f;
            psum += p[jj];
        }
        s += psum;

        unsigned u[4];
#pragma unroll
        for (int w = 0; w < 4; w++) u[w] = cvt_pk_bf16(p[2 * w], p[2 * w + 1]);
        bf16x8 pa = *(const bf16x8*)u;
#pragma unroll
        for (int t = 0; t < 8; t++)
            acc[t] = __builtin_amdgcn_mfma_f32_16x16x32_bf16(pa, hf[t], acc[t], 0, 0, 0);
    }

    // ---- cross-wave sum combine ----
    s += __shfl_xor(s, 16);
    s += __shfl_xor(s, 32);
    if (l < 16) lds_s[wv][lr] = s;

    if (wv < 4) {
#pragma unroll
        for (int t = 0; t < 8; t++)
#pragma unroll
            for (int r = 0; r < 4; r++)
                accbuf[wv][lg * 4 + r][t * 16 + lr] = acc[t][r];
    }
    __syncthreads();
    if (wv >= 4) {
#pragma unroll
        for (int t = 0; t < 8; t++)
#pragma unroll
            for (int r = 0; r < 4; r++)
                accbuf[wv - 4][lg * 4 + r][t * 16 + lr] += acc[t][r];
    }
    if (tid < 16) {
        float st = 0.f;
#pragma unroll
        for (int w = 0; w < 8; w++) st += lds_s[w][tid];
        lds_inv[tid] = 1.0f / st;
    }
    __syncthreads();

    {
        int row = tid >> 5;
        int c4 = (tid & 31) * 4;
        float4 s0 = *(const float4*)&accbuf[0][row][c4];
        float4 s1 = *(const float4*)&accbuf[1][row][c4];
        float4 s2 = *(const float4*)&accbuf[2][row][c4];
        float4 s3 = *(const float4*)&accbuf[3][row][c4];
        float inv = lds_inv[row];
        float4 o;
        o.x = (s0.x + s1.x + s2.x + s3.x) * inv;
        o.y = (s0.y + s1.y + s2.y + s3.y) * inv;
        o.z = (s0.z + s1.z + s2.z + s3.z) * inv;
        o.w = (s0.w + s1.w + s2.w + s3.w) * inv;
        *(float4*)&out[((size_t)b * NN + i0 + row) * FOUT + c4] = o;
    }
}

extern "C" void kernel_launch(void* const* d_in, const int* in_sizes, int n_in,
                              void* d_out, int out_size, void* d_ws, size_t ws_size,
                              hipStream_t stream) {
    const float* x  = (const float*)d_in[0];
    const float* W  = (const float*)d_in[1];
    const float* a1 = (const float*)d_in[2];
    const float* a2 = (const float*)d_in[3];
    const int* adj  = (const int*)d_in[4];
    // d_in[5] = adj_tree (unused by reference forward)
    const int* d1p  = (const int*)d_in[6];
    const int* d2p  = (const int*)d_in[7];
    float* out = (float*)d_out;

    char* ws = (char*)d_ws;
    unsigned short* hbuf = (unsigned short*)(ws);                       // 2 MB
    float* t1            = (float*)(ws + 2u * 1024 * 1024);             // 32 KB
    float* t2            = (float*)(ws + 2u * 1024 * 1024 + 32 * 1024); // 32 KB
    unsigned short* whi  = (unsigned short*)(ws + 2u * 1024 * 1024 + 64 * 1024);  // 128 KB
    unsigned short* wlo  = (unsigned short*)(ws + 2u * 1024 * 1024 + 192 * 1024); // 128 KB
    unsigned char* maskb = (unsigned char*)(ws + 2u * 1024 * 1024 + 320 * 1024);  // 2 MB

    k_stream<<<dim3(2080), dim3(256), 0, stream>>>(adj, d1p, d2p, W, maskb, whi, wlo);
    k_h<<<dim3(512), dim3(256), 0, stream>>>(x, whi, wlo, a1, a2, hbuf, t1, t2);
    k_attn<<<dim3(512), dim3(512), 0, stream>>>(maskb, t1, t2, hbuf, out);
}